// Round 15
// baseline (179.865 us; speedup 1.0000x reference)
//
#include <hip/hip_runtime.h>
#include <hip/hip_bf16.h>

#define BS 16
#define LQ 300
#define DIM 256
#define NH 8
#define HD 32
#define SUMP 16
#define LV 8500
#define NQ (BS*LQ)       // 4800
#define MROWS (BS*LV)    // 136000
#define RS 40            // small-GEMM staging LDS row stride (shorts)
#define AS 264           // K1 A-tile LDS row stride (shorts): 528B, 16B-aligned rows, 2-way banks
#define CS 264           // K1 C-tile LDS row stride (shorts)
#define NVAL 768         // persistent val blocks
#define NTILE 4250       // 136000 / 32

typedef __bf16 bf16x4 __attribute__((ext_vector_type(4)));
typedef __bf16 bf16x8 __attribute__((ext_vector_type(8)));
typedef float f32x4 __attribute__((ext_vector_type(4)));

__device__ __forceinline__ bf16x4 cvt8B(float4 a) {
    bf16x4 r;
    r[0] = (__bf16)a.x; r[1] = (__bf16)a.y; r[2] = (__bf16)a.z; r[3] = (__bf16)a.w;
    return r;
}
__device__ __forceinline__ bf16x8 cvt16B(float4 a, float4 b) {
    bf16x8 r;
    r[0] = (__bf16)a.x; r[1] = (__bf16)a.y; r[2] = (__bf16)a.z; r[3] = (__bf16)a.w;
    r[4] = (__bf16)b.x; r[5] = (__bf16)b.y; r[6] = (__bf16)b.z; r[7] = (__bf16)b.w;
    return r;
}

// ---- K0: W_val -> bf16 k-panel wvb[k>>3][n] (makes B frags coalesced)
__global__ __launch_bounds__(256) void k_cvtB(
    const float* __restrict__ Wv, bf16x8* __restrict__ out)
{
    const int idx = blockIdx.x * 256 + threadIdx.x;   // 8192 = 32 kp x 256 n
    const int n = idx & 255, kp = idx >> 8;
    const float4 a0 = *(const float4*)(Wv + n * 256 + kp * 8);
    const float4 a1 = *(const float4*)(Wv + n * 256 + kp * 8 + 4);
    out[kp * 256 + n] = cvt16B(a0, a1);
}

// ---- R3-proven small-GEMM body (dbuf LDS, bf16 staging). W_ pre-offset. --
__device__ __forceinline__ void small_gemm_body(
    unsigned short* SH, const float* A_, const float* W_, int M_, int bm,
    int t, f32x4 (&acc)[4][4])
{
    unsigned short* const A0 = SH;
    unsigned short* const A1 = SH + 5120;
    unsigned short* const B0 = SH + 10240;
    unsigned short* const B1 = SH + 15360;
    const int lane = t & 63, wid = t >> 6;
    const int wm = (wid >> 1) * 64, wn = (wid & 1) * 64;
    const int fra = lane & 15;
    const int koff = (lane >> 4) * 8;
    const int srow = t >> 3;
    const int scol = (t & 7) * 4;
    unsigned aoff[4];
    const float* pb0 = W_ + (long)srow * 256 + scol;
    #pragma unroll
    for (int u = 0; u < 4; ++u) {
        long gr = (long)bm * 128 + u * 32 + srow;
        if (gr > M_ - 1) gr = M_ - 1;
        aoff[u] = (unsigned)(gr * 256 + scol);
    }
    const int lw = srow * RS + scol;
    {
        #pragma unroll
        for (int u = 0; u < 4; ++u) {
            float4 a = *(const float4*)(A_ + aoff[u]);
            float4 b = *(const float4*)(pb0 + u * 32 * 256);
            *(bf16x4*)&A0[lw + u * 32 * RS] = cvt8B(a);
            *(bf16x4*)&B0[lw + u * 32 * RS] = cvt8B(b);
        }
    }
    __syncthreads();
    #pragma unroll
    for (int kt = 0; kt < 8; ++kt) {
        unsigned short* Ac = (kt & 1) ? A1 : A0;
        unsigned short* An = (kt & 1) ? A0 : A1;
        unsigned short* Bc = (kt & 1) ? B1 : B0;
        unsigned short* Bn = (kt & 1) ? B0 : B1;
        float4 na[4], nb[4];
        if (kt < 7) {
            const int k0 = (kt + 1) * 32;
            #pragma unroll
            for (int u = 0; u < 4; ++u) {
                na[u] = *(const float4*)(A_ + aoff[u] + k0);
                nb[u] = *(const float4*)(pb0 + u * 32 * 256 + k0);
            }
        }
        bf16x8 af[4], bfv[4];
        #pragma unroll
        for (int i = 0; i < 4; ++i)
            af[i] = *(const bf16x8*)&Ac[(wm + i * 16 + fra) * RS + koff];
        #pragma unroll
        for (int j = 0; j < 4; ++j)
            bfv[j] = *(const bf16x8*)&Bc[(wn + j * 16 + fra) * RS + koff];
        #pragma unroll
        for (int i = 0; i < 4; ++i)
            #pragma unroll
            for (int j = 0; j < 4; ++j)
                acc[i][j] = __builtin_amdgcn_mfma_f32_16x16x32_bf16(
                    bfv[j], af[i], acc[i][j], 0, 0, 0);
        if (kt < 7) {
            #pragma unroll
            for (int u = 0; u < 4; ++u) {
                *(bf16x4*)&An[lw + u * 32 * RS] = cvt8B(na[u]);
                *(bf16x4*)&Bn[lw + u * 32 * RS] = cvt8B(nb[u]);
            }
        }
        __syncthreads();
    }
}

// ---- K1 body: PERSISTENT grid-stride val GEMM with tile-level double
// buffer. Per tile: issue next tile's 8 reg-loads FIRST (stay in flight
// through the whole kt loop -> continuous HBM issuance), compute current
// tile from LDS buf[parity], then cvt+ds_write next-A into buf[parity^1]
// (R11-proven staging map), stage C in its own LDS region, 2 barriers/tile.
__device__ __forceinline__ void valgemm_persistent(
    unsigned short* SH, int blk, int t,
    const float* value, const bf16x8* wvbp, const float* bv,
    unsigned short* vout)
{
    unsigned short* const Abuf[2] = { SH, SH + 32 * AS };
    unsigned short* const Cst = SH + 64 * AS;

    const int lane = t & 63, wid = t >> 6;
    const int wn = wid * 64;
    const int fra = lane & 15;
    const int g = lane >> 4;               // k-subgroup 0..3
    const int koff = g * 8;

    // staging map (R11-proven): granule f = u*256+t, row=f>>6, col4=f&63
    // prologue: stage first tile synchronously into Abuf[0]
    {
        const float* src = value + (long)blk * 32 * 256;
        float4 s0[8];
        #pragma unroll
        for (int u = 0; u < 8; ++u) s0[u] = *(const float4*)(src + (u * 256 + t) * 4);
        #pragma unroll
        for (int u = 0; u < 8; ++u) {
            const int f = u * 256 + t, row = f >> 6, col4 = f & 63;
            *(bf16x4*)&Abuf[0][row * AS + col4 * 4] = cvt8B(s0[u]);
        }
    }
    __syncthreads();

    const bf16x8* wvb_base = wvbp + wn + fra + g * 256;
    int parity = 0;

    for (int tile = blk; tile < NTILE; tile += NVAL) {
        const int nxt = tile + NVAL;
        const bool has = nxt < NTILE;
        // issue next tile's loads FIRST (in flight during compute)
        float4 nx[8];
        if (has) {
            const float* src = value + (long)nxt * 32 * 256;
            #pragma unroll
            for (int u = 0; u < 8; ++u) nx[u] = *(const float4*)(src + (u * 256 + t) * 4);
        }

        // compute current tile
        f32x4 acc[2][4] = {};
        const unsigned short* Ac = Abuf[parity];
        #pragma unroll
        for (int kt = 0; kt < 8; ++kt) {
            bf16x8 bfv[4];
            #pragma unroll
            for (int j = 0; j < 4; ++j) bfv[j] = wvb_base[kt * 1024 + j * 16];
            bf16x8 af[2];
            #pragma unroll
            for (int i = 0; i < 2; ++i)
                af[i] = *(const bf16x8*)&Ac[(i * 16 + fra) * AS + kt * 32 + koff];
            #pragma unroll
            for (int i = 0; i < 2; ++i)
                #pragma unroll
                for (int j = 0; j < 4; ++j)
                    acc[i][j] = __builtin_amdgcn_mfma_f32_16x16x32_bf16(
                        bfv[j], af[i], acc[i][j], 0, 0, 0);   // lane: m=i*16+fra, 4 consec n
        }

        // stage next-A into the other buffer (loads long since in flight)
        if (has) {
            #pragma unroll
            for (int u = 0; u < 8; ++u) {
                const int f = u * 256 + t, row = f >> 6, col4 = f & 63;
                *(bf16x4*)&Abuf[parity ^ 1][row * AS + col4 * 4] = cvt8B(nx[u]);
            }
        }

        // stage C (bf16) into Cst
        const int nreg = g * 4;
        #pragma unroll
        for (int j = 0; j < 4; ++j) {
            const int n0 = wn + j * 16 + nreg;
            const float4 bj = *(const float4*)&bv[n0];
            #pragma unroll
            for (int i = 0; i < 2; ++i) {
                const int m = i * 16 + fra;
                float4 v;
                v.x = acc[i][j][0] + bj.x;
                v.y = acc[i][j][1] + bj.y;
                v.z = acc[i][j][2] + bj.z;
                v.w = acc[i][j][3] + bj.w;
                *(bf16x4*)&Cst[m * CS + n0] = cvt8B(v);
            }
        }
        __syncthreads();   // next-A + C staged visible

        // coalesced C copy-out
        #pragma unroll
        for (int u = 0; u < 4; ++u) {
            const int f = u * 256 + t;
            const int row = f >> 5, c16 = f & 31;
            *(uint4*)&vout[((long)tile * 32 + row) * 256 + c16 * 8] =
                *(const uint4*)&Cst[row * CS + c16 * 8];
        }
        __syncthreads();   // protect Cst (and buffers) across iterations
        parity ^= 1;
    }
}

// ---- K1+K2 FUSED: blocks 0..113 locattn; blocks 114..881 persistent val.
__global__ __launch_bounds__(256, 3) void k_fused1(
    const float* __restrict__ value, const bf16x8* __restrict__ wvbp,
    const float* __restrict__ bv, unsigned short* __restrict__ vout,
    const float* __restrict__ query,
    const float* __restrict__ Woff, const float* __restrict__ boff,
    const float* __restrict__ Wattn, const float* __restrict__ battn,
    const float* __restrict__ refp,
    float* __restrict__ loc, float* __restrict__ aw)
{
    __shared__ unsigned short SH[96 * AS];   // 50.7KB: val needs all; locattn uses 40KB
    const int t = threadIdx.x;
    const int id = blockIdx.x;

    if (id >= 114) {
        valgemm_persistent(SH, id - 114, t, value, wvbp, bv, vout);
        return;
    }

    // ---- locattn path (R13-verified) ----
    const int bm = id / 3, bn = id % 3;
    const float* Wsel = (bn < 2) ? (Woff + (long)bn * 128 * 256) : Wattn;
    f32x4 acc[4][4] = {};
    small_gemm_body(SH, query, Wsel, NQ, bm, t, acc);

    const int lane = t & 63, wid = t >> 6;
    const int wm = (wid >> 1) * 64, wn = (wid & 1) * 64;
    const int fra = lane & 15;
    const int nreg = (lane >> 4) * 4;
    if (bn < 2) {
        float4 bj[4];
        #pragma unroll
        for (int j = 0; j < 4; ++j)
            bj[j] = *(const float4*)&boff[bn * 128 + wn + j * 16 + nreg];
        #pragma unroll
        for (int i = 0; i < 4; ++i) {
            const long grow = (long)bm * 128 + wm + i * 16 + fra;
            if (grow < NQ) {
                const float4 rp = *(const float4*)&refp[grow * 4];
                const float sx = 0.125f * rp.z, sy = 0.125f * rp.w;
                #pragma unroll
                for (int j = 0; j < 4; ++j) {
                    float4 v;
                    v.x = rp.x + (acc[i][j][0] + bj[j].x) * sx;
                    v.y = rp.y + (acc[i][j][1] + bj[j].y) * sy;
                    v.z = rp.x + (acc[i][j][2] + bj[j].z) * sx;
                    v.w = rp.y + (acc[i][j][3] + bj[j].w) * sy;
                    *(float4*)&loc[grow * 256 + bn * 128 + wn + j * 16 + nreg] = v;
                }
            }
        }
    } else {
        #pragma unroll
        for (int i = 0; i < 4; ++i) {
            const long grow = (long)bm * 128 + wm + i * 16 + fra;
            #pragma unroll
            for (int j = 0; j < 4; ++j) {
                const int n0 = wn + j * 16 + nreg;
                const float4 bj = *(const float4*)&battn[n0];
                float vx = acc[i][j][0] + bj.x;
                float vy = acc[i][j][1] + bj.y;
                float vz = acc[i][j][2] + bj.z;
                float vw = acc[i][j][3] + bj.w;
                float mx = fmaxf(fmaxf(vx, vy), fmaxf(vz, vw));
                mx = fmaxf(mx, __shfl_xor(mx, 16));
                mx = fmaxf(mx, __shfl_xor(mx, 32));
                float ex = expf(vx - mx), ey = expf(vy - mx);
                float ez = expf(vz - mx), ew = expf(vw - mx);
                float s = ex + ey + ez + ew;
                s += __shfl_xor(s, 16);
                s += __shfl_xor(s, 32);
                const float inv = 1.f / s;
                if (grow < NQ) {
                    const int hh = (wn >> 4) + j;
                    float4 o;
                    o.x = ex * inv; o.y = ey * inv; o.z = ez * inv; o.w = ew * inv;
                    *(float4*)&aw[(grow * 8 + hh) * 16 + nreg] = o;
                }
            }
        }
    }
}

// ---- K4: out = sampled @ W_out^T + b_out (MFMA, fp32 direct stores) ----
__global__ __launch_bounds__(256) void k_gemm_out(
    const float* __restrict__ A, const float* __restrict__ W,
    const float* __restrict__ bias, float* __restrict__ out)
{
    __shared__ unsigned short SH[20480];
    const int t = threadIdx.x;
    const int bm = blockIdx.x, bn = blockIdx.y;
    const float* Wsel = W + (long)bn * 128 * 256;
    f32x4 acc[4][4] = {};
    small_gemm_body(SH, A, Wsel, NQ, bm, t, acc);

    const int lane = t & 63, wid = t >> 6;
    const int wm = (wid >> 1) * 64, wn = (wid & 1) * 64;
    const int fra = lane & 15;
    const int nreg = (lane >> 4) * 4;
    #pragma unroll
    for (int j = 0; j < 4; ++j) {
        const int nn = bn * 128 + wn + j * 16 + nreg;
        const float4 bj = *(const float4*)&bias[nn];
        #pragma unroll
        for (int i = 0; i < 4; ++i) {
            const long grow = (long)bm * 128 + wm + i * 16 + fra;
            if (grow < NQ) {
                float4 v;
                v.x = acc[i][j][0] + bj.x;
                v.y = acc[i][j][1] + bj.y;
                v.z = acc[i][j][2] + bj.z;
                v.w = acc[i][j][3] + bj.w;
                *(float4*)&out[grow * 256 + nn] = v;
            }
        }
    }
}

// ---------------- K3: bilinear sampling + attention-weighted sum ---------
// Wave = one (qg,h). Lane = (channel-pair cp = lane&15, level q = lane>>4).
// Branchless: clamped indices + validity-scaled weights (R12-verified).
__global__ __launch_bounds__(256) void k_sample(
    const unsigned short* __restrict__ vbf, const float* __restrict__ loc,
    const float* __restrict__ aw, float* __restrict__ sampled)
{
    const int t = threadIdx.x;
    const int wid = t >> 6, lane = t & 63;
    const int id = blockIdx.x * 4 + wid;   // qg*8 + h
    const int h = id & 7;
    const int qg = id >> 3;
    const int b = qg / LQ;
    const int cp = lane & 15;              // channels 2cp, 2cp+1
    const int q = lane >> 4;               // level 0..3

    const int WLs[4] = {80, 40, 20, 10};
    const int SVs[4] = {0, 6400, 8000, 8400};
    const int Wl = WLs[q];
    const unsigned short* vb = vbf + (long)b * LV * 256 + (long)SVs[q] * 256 + h * 32 + cp * 2;

    const float* locp = loc + (long)id * 32 + q * 8;   // this level's 4 pts x 2
    const float* awp  = aw  + (long)id * 16 + q * 4;

    const float4 l01 = *(const float4*)locp;
    const float4 l23 = *(const float4*)(locp + 4);
    const float4 aw4 = *(const float4*)awp;
    const float lx[4] = {l01.x, l01.z, l23.x, l23.z};
    const float ly[4] = {l01.y, l01.w, l23.y, l23.w};
    const float awv[4] = {aw4.x, aw4.y, aw4.z, aw4.w};

    float ax = 0.f, ay = 0.f;
    unsigned uu[4][4];
    float wc[4][4];
    #pragma unroll
    for (int k = 0; k < 4; ++k) {
        const float x = lx[k] * Wl - 0.5f, y = ly[k] * Wl - 0.5f;
        const float x0f = floorf(x), y0f = floorf(y);
        const float wx = x - x0f, wy = y - y0f;
        const int x0 = (int)x0f, y0 = (int)y0f;
        const int x1 = x0 + 1, y1 = y0 + 1;
        const int xc0 = min(max(x0, 0), Wl - 1), xc1 = min(max(x1, 0), Wl - 1);
        const int yc0 = min(max(y0, 0), Wl - 1), yc1 = min(max(y1, 0), Wl - 1);
        const float fx0 = (x0 >= 0 && x0 < Wl) ? 1.f : 0.f;
        const float fx1 = (x1 >= 0 && x1 < Wl) ? 1.f : 0.f;
        const float fy0 = (y0 >= 0 && y0 < Wl) ? 1.f : 0.f;
        const float fy1 = (y1 >= 0 && y1 < Wl) ? 1.f : 0.f;
        wc[k][0] = awv[k] * (1.f - wy) * (1.f - wx) * fy0 * fx0;
        wc[k][1] = awv[k] * (1.f - wy) * wx * fy0 * fx1;
        wc[k][2] = awv[k] * wy * (1.f - wx) * fy1 * fx0;
        wc[k][3] = awv[k] * wy * wx * fy1 * fx1;
        uu[k][0] = *(const unsigned*)&vb[(unsigned)((yc0 * Wl + xc0) * 256)];
        uu[k][1] = *(const unsigned*)&vb[(unsigned)((yc0 * Wl + xc1) * 256)];
        uu[k][2] = *(const unsigned*)&vb[(unsigned)((yc1 * Wl + xc0) * 256)];
        uu[k][3] = *(const unsigned*)&vb[(unsigned)((yc1 * Wl + xc1) * 256)];
    }
    #pragma unroll
    for (int k = 0; k < 4; ++k)
        #pragma unroll
        for (int c = 0; c < 4; ++c) {
            ax = fmaf(wc[k][c], __uint_as_float((uu[k][c] & 0xffffu) << 16), ax);
            ay = fmaf(wc[k][c], __uint_as_float(uu[k][c] & 0xffff0000u), ay);
        }
    ax += __shfl_xor(ax, 16); ay += __shfl_xor(ay, 16);
    ax += __shfl_xor(ax, 32); ay += __shfl_xor(ay, 32);
    if (q == 0) {
        float2 o; o.x = ax; o.y = ay;
        *(float2*)&sampled[(long)qg * 256 + h * 32 + cp * 2] = o;
    }
}

extern "C" void kernel_launch(void* const* d_in, const int* in_sizes, int n_in,
                              void* d_out, int out_size, void* d_ws, size_t ws_size,
                              hipStream_t stream)
{
    const float* query = (const float*)d_in[0];
    const float* refp  = (const float*)d_in[1];
    const float* value = (const float*)d_in[2];
    const float* Woff  = (const float*)d_in[3];
    const float* boff  = (const float*)d_in[4];
    const float* Wattn = (const float*)d_in[5];
    const float* battn = (const float*)d_in[6];
    const float* Wval  = (const float*)d_in[7];
    const float* bval  = (const float*)d_in[8];
    const float* Wout  = (const float*)d_in[9];
    const float* bout  = (const float*)d_in[10];

    // total footprint = 81,920,000 B (proven-safe)
    char* ws = (char*)d_ws;
    unsigned short* vbf = (unsigned short*)ws;                 // [0, 69,632,000)
    float* loc     = (float*)(ws + 69632000);                  // 4,915,200
    float* aw      = (float*)(ws + 74547200);                  // 2,457,600
    bf16x8* wvb    = (bf16x8*)(ws + 77004800);                 //   131,072 (dead after k_fused1)
    float* sampled = (float*)(ws + 77004800);                  // 4,915,200 (aliases wvb, written later)

    hipLaunchKernelGGL(k_cvtB, dim3(32), dim3(256), 0, stream, Wval, wvb);
    hipLaunchKernelGGL(k_fused1, dim3(114 + NVAL), dim3(256), 0, stream,
                       value, wvb, bval, vbf,
                       query, Woff, boff, Wattn, battn, refp, loc, aw);
    hipLaunchKernelGGL(k_sample, dim3(9600), dim3(256), 0, stream,
                       vbf, loc, aw, sampled);
    hipLaunchKernelGGL(k_gemm_out, dim3(38, 2), dim3(256), 0, stream,
                       sampled, Wout, bout, (float*)d_out);
}

// Round 16
// 89.159 us; speedup vs baseline: 2.0174x; 2.0174x over previous
//
#include <hip/hip_runtime.h>
#include <hip/hip_bf16.h>

#define BS 16
#define LQ 300
#define DIM 256
#define NH 8
#define HD 32
#define SUMP 16
#define LV 8500
#define NQ (BS*LQ)       // 4800
#define MROWS (BS*LV)    // 136000
#define RS 40            // small-GEMM staging LDS row stride (shorts)
#define CS 264           // K1 C-tile LDS row stride (shorts)

typedef __bf16 bf16x4 __attribute__((ext_vector_type(4)));
typedef __bf16 bf16x8 __attribute__((ext_vector_type(8)));
typedef float f32x4 __attribute__((ext_vector_type(4)));

__device__ __forceinline__ bf16x4 cvt8B(float4 a) {
    bf16x4 r;
    r[0] = (__bf16)a.x; r[1] = (__bf16)a.y; r[2] = (__bf16)a.z; r[3] = (__bf16)a.w;
    return r;
}
__device__ __forceinline__ bf16x8 cvt16B(float4 a, float4 b) {
    bf16x8 r;
    r[0] = (__bf16)a.x; r[1] = (__bf16)a.y; r[2] = (__bf16)a.z; r[3] = (__bf16)a.w;
    r[4] = (__bf16)b.x; r[5] = (__bf16)b.y; r[6] = (__bf16)b.z; r[7] = (__bf16)b.w;
    return r;
}

// ---- K0: W_val -> bf16 k-panel wvb[k>>3][n] (makes B frags coalesced)
__global__ __launch_bounds__(256) void k_cvtB(
    const float* __restrict__ Wv, bf16x8* __restrict__ out)
{
    const int idx = blockIdx.x * 256 + threadIdx.x;   // 8192 = 32 kp x 256 n
    const int n = idx & 255, kp = idx >> 8;
    const float4 a0 = *(const float4*)(Wv + n * 256 + kp * 8);
    const float4 a1 = *(const float4*)(Wv + n * 256 + kp * 8 + 4);
    out[kp * 256 + n] = cvt16B(a0, a1);
}

// ---- R3-proven small-GEMM body (dbuf LDS, bf16 staging). W_ pre-offset. --
__device__ __forceinline__ void small_gemm_body(
    unsigned short* SH, const float* A_, const float* W_, int M_, int bm,
    int t, f32x4 (&acc)[4][4])
{
    unsigned short* const A0 = SH;
    unsigned short* const A1 = SH + 5120;
    unsigned short* const B0 = SH + 10240;
    unsigned short* const B1 = SH + 15360;
    const int lane = t & 63, wid = t >> 6;
    const int wm = (wid >> 1) * 64, wn = (wid & 1) * 64;
    const int fra = lane & 15;
    const int koff = (lane >> 4) * 8;
    const int srow = t >> 3;
    const int scol = (t & 7) * 4;
    unsigned aoff[4];
    const float* pb0 = W_ + (long)srow * 256 + scol;
    #pragma unroll
    for (int u = 0; u < 4; ++u) {
        long gr = (long)bm * 128 + u * 32 + srow;
        if (gr > M_ - 1) gr = M_ - 1;
        aoff[u] = (unsigned)(gr * 256 + scol);
    }
    const int lw = srow * RS + scol;
    {
        #pragma unroll
        for (int u = 0; u < 4; ++u) {
            float4 a = *(const float4*)(A_ + aoff[u]);
            float4 b = *(const float4*)(pb0 + u * 32 * 256);
            *(bf16x4*)&A0[lw + u * 32 * RS] = cvt8B(a);
            *(bf16x4*)&B0[lw + u * 32 * RS] = cvt8B(b);
        }
    }
    __syncthreads();
    #pragma unroll
    for (int kt = 0; kt < 8; ++kt) {
        unsigned short* Ac = (kt & 1) ? A1 : A0;
        unsigned short* An = (kt & 1) ? A0 : A1;
        unsigned short* Bc = (kt & 1) ? B1 : B0;
        unsigned short* Bn = (kt & 1) ? B0 : B1;
        float4 na[4], nb[4];
        if (kt < 7) {
            const int k0 = (kt + 1) * 32;
            #pragma unroll
            for (int u = 0; u < 4; ++u) {
                na[u] = *(const float4*)(A_ + aoff[u] + k0);
                nb[u] = *(const float4*)(pb0 + u * 32 * 256 + k0);
            }
        }
        bf16x8 af[4], bfv[4];
        #pragma unroll
        for (int i = 0; i < 4; ++i)
            af[i] = *(const bf16x8*)&Ac[(wm + i * 16 + fra) * RS + koff];
        #pragma unroll
        for (int j = 0; j < 4; ++j)
            bfv[j] = *(const bf16x8*)&Bc[(wn + j * 16 + fra) * RS + koff];
        #pragma unroll
        for (int i = 0; i < 4; ++i)
            #pragma unroll
            for (int j = 0; j < 4; ++j)
                acc[i][j] = __builtin_amdgcn_mfma_f32_16x16x32_bf16(
                    bfv[j], af[i], acc[i][j], 0, 0, 0);
        if (kt < 7) {
            #pragma unroll
            for (int u = 0; u < 4; ++u) {
                *(bf16x4*)&An[lw + u * 32 * RS] = cvt8B(na[u]);
                *(bf16x4*)&Bn[lw + u * 32 * RS] = cvt8B(nb[u]);
            }
        }
        __syncthreads();
    }
}

// ---- K1 body: one-shot-K val GEMM (M=32 x N=256 x K=256), A staged fp32
// via ASYNC global_load_lds width=16 (no VGPR round-trip). LDS linear
// [32][256]f32 with XOR-16B-granule swizzle realized by pre-swizzling the
// per-lane GLOBAL address (rule #21: linear dest + inv-swz source + swz read).
// Row r granule p holds global granule p^(r&7); frag reads hit 32 banks
// 2-way (free). fp32->bf16 cvt moved to frag-read (bit-identical RNE).
__device__ __forceinline__ void valgemm_body(
    unsigned short* SH, int bm, int t,
    const float* value, const bf16x8* wvbp, const float* bv,
    unsigned short* vout)
{
    const int lane = t & 63, wid = t >> 6;
    const int wn = wid * 64;
    const int fra = lane & 15;
    const int g = lane >> 4;

    // ---- stage A tile: 8 async 1KB wave-loads per wave, one barrier ----
    const char* srcb = (const char*)(value + (long)bm * 32 * 256);
    char* shb = (char*)SH;
    #pragma unroll
    for (int u = 0; u < 8; ++u) {
        const int row = wid * 8 + u;           // r&7 == u
        const char* gp = srcb + row * 1024 + ((lane ^ u) * 16);
        __builtin_amdgcn_global_load_lds(
            (const __attribute__((address_space(1))) void*)gp,
            (__attribute__((address_space(3))) void*)(shb + row * 1024),
            16, 0, 0);
    }
    __syncthreads();                           // compiler drains vmcnt here

    // ---- 8 k-steps of MFMA + loads, no barriers ----
    f32x4 acc[2][4] = {};
    const bf16x8* wvb_base = wvbp + wn + fra + g * 256;
    const float* shf = (const float*)SH;
    const int s = fra & 7;
    #pragma unroll
    for (int kt = 0; kt < 8; ++kt) {
        bf16x8 bfv[4];
        #pragma unroll
        for (int j = 0; j < 4; ++j) bfv[j] = wvb_base[kt * 1024 + j * 16];
        bf16x8 af[2];
        #pragma unroll
        for (int i = 0; i < 2; ++i) {
            const int r = i * 16 + fra;
            const int G = kt * 8 + g * 2;      // first 16B granule of the frag
            float4 f0 = *(const float4*)(shf + r * 256 + ((G ^ s) * 4));
            float4 f1 = *(const float4*)(shf + r * 256 + (((G + 1) ^ s) * 4));
            af[i] = cvt16B(f0, f1);
        }
        #pragma unroll
        for (int i = 0; i < 2; ++i)
            #pragma unroll
            for (int j = 0; j < 4; ++j)
                acc[i][j] = __builtin_amdgcn_mfma_f32_16x16x32_bf16(
                    bfv[j], af[i], acc[i][j], 0, 0, 0);
    }

    __syncthreads();                       // A-tile dead; reuse SH as C[32][CS]
    const int nreg = g * 4;
    #pragma unroll
    for (int j = 0; j < 4; ++j) {
        const int n0 = wn + j * 16 + nreg;
        const float4 bj = *(const float4*)&bv[n0];
        #pragma unroll
        for (int i = 0; i < 2; ++i) {
            const int m = i * 16 + fra;
            float4 v;
            v.x = acc[i][j][0] + bj.x;
            v.y = acc[i][j][1] + bj.y;
            v.z = acc[i][j][2] + bj.z;
            v.w = acc[i][j][3] + bj.w;
            *(bf16x4*)&SH[m * CS + n0] = cvt8B(v);
        }
    }
    __syncthreads();
    #pragma unroll
    for (int u = 0; u < 4; ++u) {
        const int f = u * 256 + t;
        const int row = f >> 5, c16 = f & 31;
        *(uint4*)&vout[((long)bm * 32 + row) * 256 + c16 * 8] =
            *(const uint4*)&SH[row * CS + c16 * 8];
    }
}

// ---- K1+K2 FUSED: blocks 0..113 run locattn (independent of K1), blocks
// 114..4363 run the val GEMM. locattn rides in K1's idle issue slots.
__global__ __launch_bounds__(256, 4) void k_fused1(
    const float* __restrict__ value, const bf16x8* __restrict__ wvbp,
    const float* __restrict__ bv, unsigned short* __restrict__ vout,
    const float* __restrict__ query,
    const float* __restrict__ Woff, const float* __restrict__ boff,
    const float* __restrict__ Wattn, const float* __restrict__ battn,
    const float* __restrict__ refp,
    float* __restrict__ loc, float* __restrict__ aw)
{
    __shared__ unsigned short SH[20480];   // 40KB: locattn 40KB; K1 A-tile 32KB
    const int t = threadIdx.x;
    const int id = blockIdx.x;

    if (id >= 114) {
        valgemm_body(SH, id - 114, t, value, wvbp, bv, vout);
        return;
    }

    // ---- locattn path (R13-verified) ----
    const int bm = id / 3, bn = id % 3;
    const float* Wsel = (bn < 2) ? (Woff + (long)bn * 128 * 256) : Wattn;
    f32x4 acc[4][4] = {};
    small_gemm_body(SH, query, Wsel, NQ, bm, t, acc);

    const int lane = t & 63, wid = t >> 6;
    const int wm = (wid >> 1) * 64, wn = (wid & 1) * 64;
    const int fra = lane & 15;
    const int nreg = (lane >> 4) * 4;
    if (bn < 2) {
        float4 bj[4];
        #pragma unroll
        for (int j = 0; j < 4; ++j)
            bj[j] = *(const float4*)&boff[bn * 128 + wn + j * 16 + nreg];
        #pragma unroll
        for (int i = 0; i < 4; ++i) {
            const long grow = (long)bm * 128 + wm + i * 16 + fra;
            if (grow < NQ) {
                const float4 rp = *(const float4*)&refp[grow * 4];
                const float sx = 0.125f * rp.z, sy = 0.125f * rp.w;
                #pragma unroll
                for (int j = 0; j < 4; ++j) {
                    float4 v;
                    v.x = rp.x + (acc[i][j][0] + bj[j].x) * sx;
                    v.y = rp.y + (acc[i][j][1] + bj[j].y) * sy;
                    v.z = rp.x + (acc[i][j][2] + bj[j].z) * sx;
                    v.w = rp.y + (acc[i][j][3] + bj[j].w) * sy;
                    *(float4*)&loc[grow * 256 + bn * 128 + wn + j * 16 + nreg] = v;
                }
            }
        }
    } else {
        #pragma unroll
        for (int i = 0; i < 4; ++i) {
            const long grow = (long)bm * 128 + wm + i * 16 + fra;
            #pragma unroll
            for (int j = 0; j < 4; ++j) {
                const int n0 = wn + j * 16 + nreg;
                const float4 bj = *(const float4*)&battn[n0];
                float vx = acc[i][j][0] + bj.x;
                float vy = acc[i][j][1] + bj.y;
                float vz = acc[i][j][2] + bj.z;
                float vw = acc[i][j][3] + bj.w;
                float mx = fmaxf(fmaxf(vx, vy), fmaxf(vz, vw));
                mx = fmaxf(mx, __shfl_xor(mx, 16));
                mx = fmaxf(mx, __shfl_xor(mx, 32));
                float ex = expf(vx - mx), ey = expf(vy - mx);
                float ez = expf(vz - mx), ew = expf(vw - mx);
                float s = ex + ey + ez + ew;
                s += __shfl_xor(s, 16);
                s += __shfl_xor(s, 32);
                const float inv = 1.f / s;
                if (grow < NQ) {
                    const int hh = (wn >> 4) + j;
                    float4 o;
                    o.x = ex * inv; o.y = ey * inv; o.z = ez * inv; o.w = ew * inv;
                    *(float4*)&aw[(grow * 8 + hh) * 16 + nreg] = o;
                }
            }
        }
    }
}

// ---- K4: out = sampled @ W_out^T + b_out (MFMA, fp32 direct stores) ----
__global__ __launch_bounds__(256) void k_gemm_out(
    const float* __restrict__ A, const float* __restrict__ W,
    const float* __restrict__ bias, float* __restrict__ out)
{
    __shared__ unsigned short SH[20480];
    const int t = threadIdx.x;
    const int bm = blockIdx.x, bn = blockIdx.y;
    const float* Wsel = W + (long)bn * 128 * 256;
    f32x4 acc[4][4] = {};
    small_gemm_body(SH, A, Wsel, NQ, bm, t, acc);

    const int lane = t & 63, wid = t >> 6;
    const int wm = (wid >> 1) * 64, wn = (wid & 1) * 64;
    const int fra = lane & 15;
    const int nreg = (lane >> 4) * 4;
    #pragma unroll
    for (int j = 0; j < 4; ++j) {
        const int nn = bn * 128 + wn + j * 16 + nreg;
        const float4 bj = *(const float4*)&bias[nn];
        #pragma unroll
        for (int i = 0; i < 4; ++i) {
            const long grow = (long)bm * 128 + wm + i * 16 + fra;
            if (grow < NQ) {
                float4 v;
                v.x = acc[i][j][0] + bj.x;
                v.y = acc[i][j][1] + bj.y;
                v.z = acc[i][j][2] + bj.z;
                v.w = acc[i][j][3] + bj.w;
                *(float4*)&out[grow * 256 + nn] = v;
            }
        }
    }
}

// ---------------- K3: bilinear sampling + attention-weighted sum ---------
// Wave = one (qg,h). Lane = (channel-pair cp = lane&15, level q = lane>>4).
// Branchless: clamped indices + validity-scaled weights (R12-verified).
__global__ __launch_bounds__(256) void k_sample(
    const unsigned short* __restrict__ vbf, const float* __restrict__ loc,
    const float* __restrict__ aw, float* __restrict__ sampled)
{
    const int t = threadIdx.x;
    const int wid = t >> 6, lane = t & 63;
    const int id = blockIdx.x * 4 + wid;   // qg*8 + h
    const int h = id & 7;
    const int qg = id >> 3;
    const int b = qg / LQ;
    const int cp = lane & 15;              // channels 2cp, 2cp+1
    const int q = lane >> 4;               // level 0..3

    const int WLs[4] = {80, 40, 20, 10};
    const int SVs[4] = {0, 6400, 8000, 8400};
    const int Wl = WLs[q];
    const unsigned short* vb = vbf + (long)b * LV * 256 + (long)SVs[q] * 256 + h * 32 + cp * 2;

    const float* locp = loc + (long)id * 32 + q * 8;   // this level's 4 pts x 2
    const float* awp  = aw  + (long)id * 16 + q * 4;

    const float4 l01 = *(const float4*)locp;
    const float4 l23 = *(const float4*)(locp + 4);
    const float4 aw4 = *(const float4*)awp;
    const float lx[4] = {l01.x, l01.z, l23.x, l23.z};
    const float ly[4] = {l01.y, l01.w, l23.y, l23.w};
    const float awv[4] = {aw4.x, aw4.y, aw4.z, aw4.w};

    float ax = 0.f, ay = 0.f;
    unsigned uu[4][4];
    float wc[4][4];
    #pragma unroll
    for (int k = 0; k < 4; ++k) {
        const float x = lx[k] * Wl - 0.5f, y = ly[k] * Wl - 0.5f;
        const float x0f = floorf(x), y0f = floorf(y);
        const float wx = x - x0f, wy = y - y0f;
        const int x0 = (int)x0f, y0 = (int)y0f;
        const int x1 = x0 + 1, y1 = y0 + 1;
        const int xc0 = min(max(x0, 0), Wl - 1), xc1 = min(max(x1, 0), Wl - 1);
        const int yc0 = min(max(y0, 0), Wl - 1), yc1 = min(max(y1, 0), Wl - 1);
        const float fx0 = (x0 >= 0 && x0 < Wl) ? 1.f : 0.f;
        const float fx1 = (x1 >= 0 && x1 < Wl) ? 1.f : 0.f;
        const float fy0 = (y0 >= 0 && y0 < Wl) ? 1.f : 0.f;
        const float fy1 = (y1 >= 0 && y1 < Wl) ? 1.f : 0.f;
        wc[k][0] = awv[k] * (1.f - wy) * (1.f - wx) * fy0 * fx0;
        wc[k][1] = awv[k] * (1.f - wy) * wx * fy0 * fx1;
        wc[k][2] = awv[k] * wy * (1.f - wx) * fy1 * fx0;
        wc[k][3] = awv[k] * wy * wx * fy1 * fx1;
        uu[k][0] = *(const unsigned*)&vb[(unsigned)((yc0 * Wl + xc0) * 256)];
        uu[k][1] = *(const unsigned*)&vb[(unsigned)((yc0 * Wl + xc1) * 256)];
        uu[k][2] = *(const unsigned*)&vb[(unsigned)((yc1 * Wl + xc0) * 256)];
        uu[k][3] = *(const unsigned*)&vb[(unsigned)((yc1 * Wl + xc1) * 256)];
    }
    #pragma unroll
    for (int k = 0; k < 4; ++k)
        #pragma unroll
        for (int c = 0; c < 4; ++c) {
            ax = fmaf(wc[k][c], __uint_as_float((uu[k][c] & 0xffffu) << 16), ax);
            ay = fmaf(wc[k][c], __uint_as_float(uu[k][c] & 0xffff0000u), ay);
        }
    ax += __shfl_xor(ax, 16); ay += __shfl_xor(ay, 16);
    ax += __shfl_xor(ax, 32); ay += __shfl_xor(ay, 32);
    if (q == 0) {
        float2 o; o.x = ax; o.y = ay;
        *(float2*)&sampled[(long)qg * 256 + h * 32 + cp * 2] = o;
    }
}

extern "C" void kernel_launch(void* const* d_in, const int* in_sizes, int n_in,
                              void* d_out, int out_size, void* d_ws, size_t ws_size,
                              hipStream_t stream)
{
    const float* query = (const float*)d_in[0];
    const float* refp  = (const float*)d_in[1];
    const float* value = (const float*)d_in[2];
    const float* Woff  = (const float*)d_in[3];
    const float* boff  = (const float*)d_in[4];
    const float* Wattn = (const float*)d_in[5];
    const float* battn = (const float*)d_in[6];
    const float* Wval  = (const float*)d_in[7];
    const float* bval  = (const float*)d_in[8];
    const float* Wout  = (const float*)d_in[9];
    const float* bout  = (const float*)d_in[10];

    // total footprint = 81,920,000 B (proven-safe)
    char* ws = (char*)d_ws;
    unsigned short* vbf = (unsigned short*)ws;                 // [0, 69,632,000)
    float* loc     = (float*)(ws + 69632000);                  // 4,915,200
    float* aw      = (float*)(ws + 74547200);                  // 2,457,600
    bf16x8* wvb    = (bf16x8*)(ws + 77004800);                 //   131,072 (dead after k_fused1)
    float* sampled = (float*)(ws + 77004800);                  // 4,915,200 (aliases wvb, written later)

    hipLaunchKernelGGL(k_cvtB, dim3(32), dim3(256), 0, stream, Wval, wvb);
    hipLaunchKernelGGL(k_fused1, dim3(4364), dim3(256), 0, stream,
                       value, wvb, bval, vbf,
                       query, Woff, boff, Wattn, battn, refp, loc, aw);
    hipLaunchKernelGGL(k_sample, dim3(9600), dim3(256), 0, stream,
                       vbf, loc, aw, sampled);
    hipLaunchKernelGGL(k_gemm_out, dim3(38, 2), dim3(256), 0, stream,
                       sampled, Wout, bout, (float*)d_out);
}